// Round 7
// baseline (623.564 us; speedup 1.0000x reference)
//
#include <hip/hip_runtime.h>
#include <hip/hip_bf16.h>

// ZambaMambaMixer: B=2,S=2048,H=2048 -> I=4096, N=16,K=4,R=128,NH=2,HD=2048.
// Dtype model T3 (confirmed R4): inputs fp32, output fp32. Intermediates bf16.
// R5: bf16-MFMA big GEMMs (m97 structure + XOR swizzle) + coalesced scan.
// R6: chunked parallel scan (16 chunks of 128), 810us -> ~60us.
// R7: x_proj/dt GEMMs -> MFMA; compact bc buffer for scan B/C.
// R8: in_proj -> 256x256 8-phase counted-vmcnt kernel (988 TF, 0 conflicts).
// R9: out_proj -> 8-phase BM256xBN128; scan 8-deep register prefetch.
// R10: FAILED one-barrier reg-prefetch schedule; exposed gemm_dt 162us.
// R11: R8 schedule restored; gemm_dt LDS-transpose epilogue (162 -> ~13us).
// R12: (a) vmcnt waits moved to template placement: prologue vmcnt(4/3),
//      loop vmcnt(4/3) at phases 3 & 7 only (full drain table re-derived,
//      incl. iteration 0 -- deeper prologue drain required and applied).
//      (b) out_proj: split-K=2 at full BN=256 density, grid (8,16,2),
//      fp32 partials in dead gate+xsb slots (contiguous), + add kernel.
#define BB   2
#define SS   2048
#define HH   2048
#define II   4096
#define NHH  2
#define HDD  2048
#define NNS  16
#define RR   128
#define RN2  160
#define BSF  (BB*SS)   // 4096
#define CHUNKS 16
#define CT     (SS / CHUNKS)   // 128 timesteps per chunk
#define NCH    8192            // (h,b,d) channels = NHH*BB*HDD

typedef __hip_bfloat16 bf16;
typedef __attribute__((ext_vector_type(8))) short short8;
typedef __attribute__((ext_vector_type(4))) float floatx4;

__device__ inline float b2f(bf16 v) { return __bfloat162float(v); }
__device__ inline bf16  f2b(float v) { return __float2bfloat16(v); }

// async global->LDS, 16B per lane, lane L lands at ldsbase + L*16
__device__ inline void load_lds16(const bf16* g, short* l) {
    __builtin_amdgcn_global_load_lds(
        (const __attribute__((address_space(1))) void*)g,
        (__attribute__((address_space(3))) void*)l, 16, 0, 0);
}

// ---------------------------------------------------------------------------
// fp32 -> bf16 cast, 4 elems/thread
// ---------------------------------------------------------------------------
__global__ __launch_bounds__(256) void cast_f2b(
    const float* __restrict__ src, bf16* __restrict__ dst)
{
    const int idx = blockIdx.x * 256 + threadIdx.x;
    float4 v = ((const float4*)src)[idx];
    union { bf16 h[4]; uint2 u; } o;
    o.h[0] = f2b(v.x); o.h[1] = f2b(v.y); o.h[2] = f2b(v.z); o.h[3] = f2b(v.w);
    ((uint2*)dst)[idx] = o.u;
}

// x_proj_w cast with zero-padding: src [h][160][2048] -> dst [h][256][2048]
__global__ __launch_bounds__(256) void cast_pad_xpw(
    const float* __restrict__ src, bf16* __restrict__ dst)
{
    const int idx = blockIdx.x * 256 + threadIdx.x;   // over 2*256*2048/4
    const int e = idx * 4;
    const int h = e >> 19;            // 256*2048 = 2^19
    const int rem = e & ((1 << 19) - 1);
    const int row = rem >> 11;        // /2048
    union { bf16 hh[4]; uint2 u; } o;
    if (row < RN2) {
        float4 v = *(const float4*)(src + (long)h * RN2 * HDD + rem);
        o.hh[0] = f2b(v.x); o.hh[1] = f2b(v.y);
        o.hh[2] = f2b(v.z); o.hh[3] = f2b(v.w);
    } else {
        o.hh[0] = o.hh[1] = o.hh[2] = o.hh[3] = f2b(0.f);
    }
    ((uint2*)dst)[idx] = o.u;
}

// split-K reduce: out[i] = p[i] + p[i + BSF*HH], 4 floats/thread
__global__ __launch_bounds__(256) void addk(
    const float* __restrict__ p, float* __restrict__ out)
{
    const int idx = blockIdx.x * 256 + threadIdx.x;
    float4 a = ((const float4*)p)[idx];
    float4 b = ((const float4*)(p + (long)BSF * HH))[idx];
    float4 o; o.x = a.x + b.x; o.y = a.y + b.y;
    o.z = a.z + b.z; o.w = a.w + b.w;
    ((float4*)out)[idx] = o;
}

// ---------------------------------------------------------------------------
// 8-phase BM=256 x BN=BROWS MFMA NT GEMM (T2+T3+T4+T5), R8 schedule with
// R12 vmcnt placement. 512 thr = 8 waves (2m x 4n), BK=64.
// LDS: As[2][2][256][32] + Bs[2][2][BROWS][32] bf16 (dynamic).
// Phase p: ds_read frags; stage one half-tile; p==3||p==7: vmcnt(4)
// [BROWS=256; (3) for 128]; barrier; lgkmcnt(0); setprio MFMA; barrier.
// Drain table (instr counts, verified incl. iter 0 w/ prologue vmcnt(4/3)):
// every region lands >=1 barrier before first read; WAR via barriers.
// blockIdx.z = K-split (kofs = z*Kd); ldab = full row stride.
// MODE 0: n even -> C0, n odd -> C1 (bf16, col n/2, ldc). MODE 1: fp32,
// partial z stored at C0 + z*BSF*ldc.
// ---------------------------------------------------------------------------
template <int MODE, int BROWS>
__global__ __launch_bounds__(512) void gemm_8ph(
    const bf16* __restrict__ A, const bf16* __restrict__ B,
    void* __restrict__ C0v, void* __restrict__ C1v, int Kd, int ldab, int ldc)
{
    constexpr int BNW = BROWS / 4;     // per-wave n cols
    constexpr int NFR = BNW / 16;      // b fragments per wave
    extern __shared__ short smem8[];
    short* As = smem8;                 // [2][2][256][32]
    short* Bs = smem8 + 32768;         // [2][2][BROWS][32]
    const int tid  = threadIdx.x;
    const int wave = tid >> 6, lane = tid & 63;
    const int wm = wave >> 2, wn = wave & 3;
    const int l15 = lane & 15, l4 = lane >> 4;
    const int coff = (l4 ^ ((l15 >> 1) & 3)) * 8;      // swizzled chunk (shorts)
    const int nt = blockIdx.x, mt = blockIdx.y;
    const long arow0 = (long)mt * 256, brow0 = (long)nt * BROWS;
    const long kofs = (long)blockIdx.z * Kd;
    const int srow = lane >> 2;                        // staging row-in-16
    const int sgc  = (lane & 3) ^ ((lane >> 3) & 3);   // staging global chunk
    const int NT = Kd >> 6;
    const long ldk = ldab;

    floatx4 acc[8][NFR];
#pragma unroll
    for (int i = 0; i < 8; ++i)
#pragma unroll
        for (int j = 0; j < NFR; ++j) acc[i][j] = (floatx4){0.f, 0.f, 0.f, 0.f};

    auto stageA = [&](int slot, int kh, int t) {
        const int tc2 = (t < NT) ? t : (NT - 1);
        const long gb = kofs + ((long)tc2 << 6) + kh * 32 + sgc * 8;
#pragma unroll
        for (int j = 0; j < 2; ++j) {
            const int r0 = (wave * 2 + j) * 16;
            load_lds16(A + (arow0 + r0 + srow) * ldk + gb,
                       As + ((slot * 2 + kh) * 256 + r0) * 32);
        }
    };
    auto stageB = [&](int slot, int kh, int t) {
        const int tc2 = (t < NT) ? t : (NT - 1);
        const long gb = kofs + ((long)tc2 << 6) + kh * 32 + sgc * 8;
        if constexpr (BROWS == 256) {
#pragma unroll
            for (int j = 0; j < 2; ++j) {
                const int r0 = (wave * 2 + j) * 16;
                load_lds16(B + (brow0 + r0 + srow) * ldk + gb,
                           Bs + ((slot * 2 + kh) * 256 + r0) * 32);
            }
        } else {
            const int r0 = wave * 16;
            load_lds16(B + (brow0 + r0 + srow) * ldk + gb,
                       Bs + ((slot * 2 + kh) * 128 + r0) * 32);
        }
    };

    // prologue: tile0 (kh0,kh1) + tile1 (kh0); deep drain so regions (0,0)
    // AND (0,1) are landed before the loop (iter-0 safety for ph3/7 waits).
    stageA(0, 0, 0); stageB(0, 0, 0);
    stageA(0, 1, 0); stageB(0, 1, 0);
    stageA(1, 0, 1); stageB(1, 0, 1);
    if constexpr (BROWS == 256) asm volatile("s_waitcnt vmcnt(4)");
    else                        asm volatile("s_waitcnt vmcnt(3)");
    __builtin_amdgcn_s_barrier();

    short8 b_fr[NFR];
    const int NI = NT >> 1;
    for (int i = 0; i < NI; ++i) {
#pragma unroll
        for (int p = 0; p < 8; ++p) {
            const int cs = p >> 2, kh = (p >> 1) & 1, mh = p & 1;
            const int rbA = (cs * 2 + kh) * 256;
            const int rbB = (cs * 2 + kh) * BROWS;
            short8 a_fr[4];
#pragma unroll
            for (int q = 0; q < 4; ++q)
                a_fr[q] = *(const short8*)(
                    As + (rbA + wm * 128 + (mh * 4 + q) * 16 + l15) * 32 + coff);
            if (mh == 0) {
#pragma unroll
                for (int g = 0; g < NFR; ++g)
                    b_fr[g] = *(const short8*)(
                        Bs + (rbB + wn * BNW + g * 16 + l15) * 32 + coff);
            }
            // staging table (region free'd >=1 barrier before; read later)
            if      (p == 0) stageA(1, 1, 2 * i + 1);
            else if (p == 1) stageB(1, 1, 2 * i + 1);
            else if (p == 2) stageA(0, 0, 2 * i + 2);
            else if (p == 3) stageB(0, 0, 2 * i + 2);
            else if (p == 4) stageA(0, 1, 2 * i + 2);
            else if (p == 5) stageB(0, 1, 2 * i + 2);
            else if (p == 6) stageA(1, 0, 2 * i + 3);
            else             stageB(1, 0, 2 * i + 3);
            if (p == 3 || p == 7) {
                if constexpr (BROWS == 256)
                    asm volatile("s_waitcnt vmcnt(4)");
                else
                    asm volatile("s_waitcnt vmcnt(3)");
            }
            __builtin_amdgcn_s_barrier();
            asm volatile("s_waitcnt lgkmcnt(0)");
            __builtin_amdgcn_sched_barrier(0);
            __builtin_amdgcn_s_setprio(1);
#pragma unroll
            for (int q = 0; q < 4; ++q)
#pragma unroll
                for (int g = 0; g < NFR; ++g)
                    acc[mh * 4 + q][g] = __builtin_amdgcn_mfma_f32_16x16x32_bf16(
                        a_fr[q], b_fr[g], acc[mh * 4 + q][g], 0, 0, 0);
            __builtin_amdgcn_s_setprio(0);
            __builtin_amdgcn_s_barrier();
        }
    }

    const long zoff = (long)blockIdx.z * BSF * ldc;
#pragma unroll
    for (int f = 0; f < 8; ++f)
#pragma unroll
        for (int g = 0; g < NFR; ++g) {
            const int gcol = nt * BROWS + wn * BNW + g * 16 + l15;
#pragma unroll
            for (int r = 0; r < 4; ++r) {
                const int grow = mt * 256 + wm * 128 + f * 16 + l4 * 4 + r;
                const float v = acc[f][g][r];
                if (MODE == 0) {
                    bf16* buf = (gcol & 1) ? (bf16*)C1v : (bf16*)C0v;
                    buf[(long)grow * ldc + (gcol >> 1)] = f2b(v);
                } else {
                    ((float*)C0v)[zoff + (long)grow * ldc + gcol] = v;
                }
            }
        }
}

// ---------------------------------------------------------------------------
// x_proj MFMA: per head h, C[bs][r] = sum_k xsb[bs][h*HD+k] * xpw[h][r][k].
// r<128 -> dtin bf16 [h][bs][128]; 128<=r<160 -> bc fp32 [h][bs][32]; else skip.
// ---------------------------------------------------------------------------
__global__ __launch_bounds__(256) void gemm_xp(
    const bf16* __restrict__ Abase, const bf16* __restrict__ Bbase,
    bf16* __restrict__ dtin, float* __restrict__ bc)
{
    const int h = blockIdx.z;
    const bf16* A = Abase + (long)h * HDD;           // lda = II
    const bf16* B = Bbase + (long)h * 256 * HDD;     // ldb = HDD
    bf16*  C0 = dtin + (long)h * BSF * RR;
    float* C1 = bc   + (long)h * BSF * 32;
    __shared__ short Asm[128 * 32];
    __shared__ short Bsm[128 * 32];
    const int tid  = threadIdx.x;
    const int wave = tid >> 6, lane = tid & 63;
    const int wr = wave >> 1, wc = wave & 1;
    const int mt = blockIdx.y, nt = blockIdx.x;
    const int rl = lane >> 2, slot = lane & 3;
    const int gchunk = slot ^ ((rl >> 1) & 3);
    const int l15 = lane & 15, l4 = lane >> 4;
    const int coff = (l4 ^ ((l15 >> 1) & 3)) * 8;

    floatx4 acc[4][4];
#pragma unroll
    for (int i = 0; i < 4; ++i)
#pragma unroll
        for (int j = 0; j < 4; ++j) acc[i][j] = (floatx4){0.f, 0.f, 0.f, 0.f};

    for (int kt = 0; kt < HDD; kt += 32) {
#pragma unroll
        for (int half = 0; half < 2; ++half) {
            const int row = wave * 32 + half * 16 + rl;
            load_lds16(A + (long)(mt * 128 + row) * II + kt + gchunk * 8,
                       Asm + (wave * 32 + half * 16) * 32);
            load_lds16(B + (long)(nt * 128 + row) * HDD + kt + gchunk * 8,
                       Bsm + (wave * 32 + half * 16) * 32);
        }
        __syncthreads();
        short8 af[4], bf[4];
#pragma unroll
        for (int f = 0; f < 4; ++f) {
            const int ra = wr * 64 + f * 16 + l15;
            const int rb = wc * 64 + f * 16 + l15;
            af[f] = *(const short8*)(Asm + ra * 32 + coff);
            bf[f] = *(const short8*)(Bsm + rb * 32 + coff);
        }
#pragma unroll
        for (int fm = 0; fm < 4; ++fm)
#pragma unroll
            for (int fn = 0; fn < 4; ++fn)
                acc[fm][fn] = __builtin_amdgcn_mfma_f32_16x16x32_bf16(
                    af[fm], bf[fn], acc[fm][fn], 0, 0, 0);
        __syncthreads();
    }

#pragma unroll
    for (int fm = 0; fm < 4; ++fm)
#pragma unroll
        for (int fn = 0; fn < 4; ++fn) {
            const int gcol = nt * 128 + wc * 64 + fn * 16 + l15;   // r-dim
#pragma unroll
            for (int r = 0; r < 4; ++r) {
                const int grow = mt * 128 + wr * 64 + fm * 16 + l4 * 4 + r; // bs
                const float v = acc[fm][fn][r];
                if (gcol < RR)
                    C0[(long)grow * RR + gcol] = f2b(v);
                else if (gcol < RN2)
                    C1[(long)grow * 32 + (gcol - RR)] = v;
            }
        }
}

// ---------------------------------------------------------------------------
// dt MFMA: per head h, C[bs][d] = sum_r dtin[h][bs][r] * dtw[h][d][r];
// then softplus(C + bias[h][d]) -> dtb[bs][h*HD+d] bf16.
// R11 epilogue: LDS transpose (float[128][33]) + __logf(1+__expf(v)) +
// 16-contiguous-bf16 stores.
// ---------------------------------------------------------------------------
__global__ __launch_bounds__(256) void gemm_dt(
    const bf16* __restrict__ dtin, const bf16* __restrict__ dtw,
    const float* __restrict__ bias, bf16* __restrict__ dtb)
{
    const int h = blockIdx.z;
    const bf16* A = dtin + (long)h * BSF * RR;   // lda = RR
    const bf16* B = dtw  + (long)h * HDD * RR;   // ldb = RR
    __shared__ float smemf[128 * 33];            // 16.9KB; aliased by staging
    short* Asm = (short*)smemf;                  // 128*32 shorts = 8KB
    short* Bsm = Asm + 128 * 32;                 // 8KB
    const int tid  = threadIdx.x;
    const int wave = tid >> 6, lane = tid & 63;
    const int wr = wave >> 1, wc = wave & 1;
    const int mt = blockIdx.y, nt = blockIdx.x;
    const int rl = lane >> 2, slot = lane & 3;
    const int gchunk = slot ^ ((rl >> 1) & 3);
    const int l15 = lane & 15, l4 = lane >> 4;
    const int coff = (l4 ^ ((l15 >> 1) & 3)) * 8;

    floatx4 acc[4][4];
#pragma unroll
    for (int i = 0; i < 4; ++i)
#pragma unroll
        for (int j = 0; j < 4; ++j) acc[i][j] = (floatx4){0.f, 0.f, 0.f, 0.f};

    for (int kt = 0; kt < RR; kt += 32) {
#pragma unroll
        for (int half = 0; half < 2; ++half) {
            const int row = wave * 32 + half * 16 + rl;
            load_lds16(A + (long)(mt * 128 + row) * RR + kt + gchunk * 8,
                       Asm + (wave * 32 + half * 16) * 32);
            load_lds16(B + (long)(nt * 128 + row) * RR + kt + gchunk * 8,
                       Bsm + (wave * 32 + half * 16) * 32);
        }
        __syncthreads();
        short8 af[4], bf[4];
#pragma unroll
        for (int f = 0; f < 4; ++f) {
            const int ra = wr * 64 + f * 16 + l15;
            const int rb = wc * 64 + f * 16 + l15;
            af[f] = *(const short8*)(Asm + ra * 32 + coff);
            bf[f] = *(const short8*)(Bsm + rb * 32 + coff);
        }
#pragma unroll
        for (int fm = 0; fm < 4; ++fm)
#pragma unroll
            for (int fn = 0; fn < 4; ++fn)
                acc[fm][fn] = __builtin_amdgcn_mfma_f32_16x16x32_bf16(
                    af[fm], bf[fn], acc[fm][fn], 0, 0, 0);
        __syncthreads();
    }

    // epilogue: 4 passes (one per fn); LDS col c' = wc*16+l15 maps to
    // global col nt*128 + (c'>>4)*64 + p*16 + (c'&15).
    const int row = tid >> 1, chf = tid & 1;
#pragma unroll
    for (int p = 0; p < 4; ++p) {
        __syncthreads();
#pragma unroll
        for (int fm = 0; fm < 4; ++fm)
#pragma unroll
            for (int r = 0; r < 4; ++r)
                smemf[(wr * 64 + fm * 16 + l4 * 4 + r) * 33 + wc * 16 + l15] =
                    acc[fm][p][r];
        __syncthreads();
        float vv[16];
#pragma unroll
        for (int q = 0; q < 4; ++q)
            *(float4*)&vv[q * 4] =
                *(const float4*)&smemf[row * 33 + chf * 16 + q * 4];
        const int gc0 = nt * 128 + chf * 64 + p * 16;
        const float* bp = bias + h * HDD + gc0;
        union { bf16 hh[16]; uint4 u4[2]; } o;
#pragma unroll
        for (int j = 0; j < 16; ++j) {
            float v = vv[j] + bp[j];
            v = (v > 20.f) ? v : __logf(1.f + __expf(v));
            o.hh[j] = f2b(v);
        }
        bf16* dst = dtb + (long)(mt * 128 + row) * II + h * HDD + gc0;
        *(uint4*)dst = o.u4[0];
        *(uint4*)(dst + 8) = o.u4[1];
    }
}

// ---------------------------------------------------------------------------
// Depthwise causal conv (K=4) + bias + SiLU. Layout (b*s, i), i contiguous.
// ---------------------------------------------------------------------------
__global__ __launch_bounds__(256) void conv_silu_kernel(
    const bf16* __restrict__ xraw, const float* __restrict__ conv_w,
    const float* __restrict__ conv_b, bf16* __restrict__ xs)
{
    const int idx = blockIdx.x * 256 + threadIdx.x;  // over BSF*II
    const int i  = idx & (II - 1);
    const int bs = idx >> 12;
    const int s  = bs & (SS - 1);
    const float4 cw = ((const float4*)conv_w)[i];
    float v = conv_b[i];
    const bf16* col = xraw + (long)bs * II + i;
    if (s >= 3) v = fmaf(b2f(col[-3 * II]), cw.x, v);
    if (s >= 2) v = fmaf(b2f(col[-2 * II]), cw.y, v);
    if (s >= 1) v = fmaf(b2f(col[-1 * II]), cw.z, v);
    v = fmaf(b2f(col[0]), cw.w, v);
    xs[idx] = f2b(v / (1.f + __expf(-v)));
}

// ---------------------------------------------------------------------------
// Chunked selective scan (R6). B/C from compact bc buffer [h][bs][32] fp32.
// R9: dt/x(/gate) loads are 8-deep register-prefetched per 8-step group.
// ---------------------------------------------------------------------------
__global__ __launch_bounds__(256) void scan_part1(
    const bf16* __restrict__ dtb, const bf16* __restrict__ xs,
    const float* __restrict__ bc, const float* __restrict__ A_log,
    float* __restrict__ Lbuf, float* __restrict__ sumdt)
{
    __shared__ float Bs[64][16];
    const int tid = threadIdx.x;
    const int c = blockIdx.x, dblk = blockIdx.y, hb = blockIdx.z;
    const int h = hb >> 1, b = hb & 1;
    const int d = dblk * 256 + tid;
    const int i = h * HDD + d;
    const int ch = hb * HDD + d;

    float st[16], Aval[16];
#pragma unroll
    for (int n = 0; n < 16; ++n) {
        Aval[n] = -__expf(A_log[(long)i * NNS + n]);
        st[n] = 0.f;
    }
    const long rowbase = (long)h * BSF + (long)b * SS + c * CT;
    const long pbase = ((long)b * SS + (long)c * CT) * II + i;
    float sdt = 0.f;
    bf16 cd[8], cx[8];
#pragma unroll
    for (int j = 0; j < 8; ++j) {
        cd[j] = dtb[pbase + (long)j * II];
        cx[j] = xs [pbase + (long)j * II];
    }

    const int sr = tid >> 2, sq = tid & 3;
    for (int tc = 0; tc < CT; tc += 64) {
        __syncthreads();
        {
            const float* src = bc + (rowbase + tc + sr) * 32 + sq * 4;
            *(float4*)&Bs[sr][sq * 4] = *(const float4*)src;
        }
        __syncthreads();
        for (int tg = 0; tg < 64; tg += 8) {
            bf16 nd[8], nx[8];
            const int tn0 = tc + tg + 8;
#pragma unroll
            for (int j = 0; j < 8; ++j) {
                int tt = tn0 + j; tt = (tt < CT) ? tt : (CT - 1);
                nd[j] = dtb[pbase + (long)tt * II];
                nx[j] = xs [pbase + (long)tt * II];
            }
#pragma unroll
            for (int j = 0; j < 8; ++j) {
                const int tl = tg + j;
                const float dtv = b2f(cd[j]);
                const float dtx = dtv * b2f(cx[j]);
                float fB[16];
#pragma unroll
                for (int q = 0; q < 4; ++q)
                    *(float4*)&fB[q * 4] = *(const float4*)&Bs[tl][q * 4];
#pragma unroll
                for (int n = 0; n < 16; ++n)
                    st[n] = fmaf(__expf(Aval[n] * dtv), st[n], dtx * fB[n]);
                sdt += dtv;
            }
#pragma unroll
            for (int j = 0; j < 8; ++j) { cd[j] = nd[j]; cx[j] = nx[j]; }
        }
    }
    float* Lp = Lbuf + ((long)c * NCH + ch) * 16;
#pragma unroll
    for (int j = 0; j < 4; ++j)
        *(float4*)&Lp[j * 4] = *(const float4*)&st[j * 4];
    sumdt[c * NCH + ch] = sdt;
}

__global__ __launch_bounds__(256) void scan_part2(
    const float* __restrict__ A_log, float* __restrict__ Lbuf,
    const float* __restrict__ sumdt)
{
    const int gid = blockIdx.x * 256 + threadIdx.x;  // NCH*16 threads
    const int ch = gid >> 4, n = gid & 15;
    const int hb = ch >> 11, d = ch & (HDD - 1);
    const int h = hb >> 1;
    const float Aval = -__expf(A_log[(long)(h * HDD + d) * NNS + n]);
    float run = 0.f;
#pragma unroll
    for (int c = 0; c < CHUNKS; ++c) {
        const long idx = ((long)c * NCH + ch) * 16 + n;
        const float Lv  = Lbuf[idx];
        const float sdt = sumdt[c * NCH + ch];
        Lbuf[idx] = run;                         // entry state for chunk c
        run = fmaf(__expf(Aval * sdt), run, Lv); // compose chunk c
    }
}

__global__ __launch_bounds__(256) void scan_part3(
    const bf16* __restrict__ dtb, const bf16* __restrict__ xs,
    const bf16* __restrict__ gate, const float* __restrict__ bc,
    const float* __restrict__ A_log, const float* __restrict__ Dp,
    const float* __restrict__ Lbuf, bf16* __restrict__ yfin)
{
    __shared__ float Bs[64][16];
    __shared__ float Cs[64][16];
    const int tid = threadIdx.x;
    const int c = blockIdx.x, dblk = blockIdx.y, hb = blockIdx.z;
    const int h = hb >> 1, b = hb & 1;
    const int d = dblk * 256 + tid;
    const int i = h * HDD + d;
    const int ch = hb * HDD + d;

    float st[16], Aval[16];
    const float* Lp = Lbuf + ((long)c * NCH + ch) * 16;
#pragma unroll
    for (int j = 0; j < 4; ++j)
        *(float4*)&st[j * 4] = *(const float4*)&Lp[j * 4];
#pragma unroll
    for (int n = 0; n < 16; ++n)
        Aval[n] = -__expf(A_log[(long)i * NNS + n]);
    const float Dv = Dp[i];

    const long rowbase = (long)h * BSF + (long)b * SS + c * CT;
    const long pbase = ((long)b * SS + (long)c * CT) * II + i;
    bf16 cd[8], cx[8], cg[8];
#pragma unroll
    for (int j = 0; j < 8; ++j) {
        cd[j] = dtb [pbase + (long)j * II];
        cx[j] = xs  [pbase + (long)j * II];
        cg[j] = gate[pbase + (long)j * II];
    }

    const int sr = tid >> 2, sq = tid & 3;
    for (int tc = 0; tc < CT; tc += 64) {
        __syncthreads();
        {
            const float* src = bc + (rowbase + tc + sr) * 32 + sq * 4;
            float4 bb = *(const float4*)src;
            float4 cc = *(const float4*)(src + 16);
            *(float4*)&Bs[sr][sq * 4] = bb;
            *(float4*)&Cs[sr][sq * 4] = cc;
        }
        __syncthreads();
        for (int tg = 0; tg < 64; tg += 8) {
            bf16 nd[8], nx[8], ng[8];
            const int tn0 = tc + tg + 8;
#pragma unroll
            for (int j = 0; j < 8; ++j) {
                int tt = tn0 + j; tt = (tt < CT) ? tt : (CT - 1);
                nd[j] = dtb [pbase + (long)tt * II];
                nx[j] = xs  [pbase + (long)tt * II];
                ng[j] = gate[pbase + (long)tt * II];
            }
            const long prow = pbase + (long)(tc + tg) * II;
#pragma unroll
            for (int j = 0; j < 8; ++j) {
                const int tl = tg + j;
                const float dtv = b2f(cd[j]);
                const float xv  = b2f(cx[j]);
                const float gv  = b2f(cg[j]);
                const float dtx = dtv * xv;
                float fB[16], fC[16];
#pragma unroll
                for (int q = 0; q < 4; ++q) {
                    *(float4*)&fB[q * 4] = *(const float4*)&Bs[tl][q * 4];
                    *(float4*)&fC[q * 4] = *(const float4*)&Cs[tl][q * 4];
                }
                float y = 0.f;
#pragma unroll
                for (int n = 0; n < 16; ++n) {
                    const float dA = __expf(Aval[n] * dtv);
                    st[n] = fmaf(dA, st[n], dtx * fB[n]);
                    y = fmaf(st[n], fC[n], y);
                }
                const float sg = gv / (1.f + __expf(-gv));
                yfin[prow + (long)j * II] = f2b((y + xv * Dv) * sg);
            }
#pragma unroll
            for (int j = 0; j < 8; ++j) { cd[j] = nd[j]; cx[j] = nx[j]; cg[j] = ng[j]; }
        }
    }
}

// ---------------------------------------------------------------------------
extern "C" void kernel_launch(void* const* d_in, const int* in_sizes, int n_in,
                              void* d_out, int out_size, void* d_ws, size_t ws_size,
                              hipStream_t stream) {
    const float* hidden     = (const float*)d_in[0];
    const float* in_proj_w  = (const float*)d_in[1];
    const float* conv_w     = (const float*)d_in[2];
    const float* conv_b     = (const float*)d_in[3];
    const float* x_proj_w   = (const float*)d_in[4];
    const float* dt_proj_w  = (const float*)d_in[5];
    const float* dt_proj_b  = (const float*)d_in[6];
    const float* A_log      = (const float*)d_in[7];
    const float* Dp         = (const float*)d_in[8];
    const float* out_proj_w = (const float*)d_in[9];
    float* out = (float*)d_out;

    const long NBI = (long)BSF * II;      // 16,777,216
    bf16* wsb   = (bf16*)d_ws;
    bf16* inw_bf  = wsb;                  // [0, 16.8M) : in_proj_w bf16, 33.5MB
    bf16* outw_bf = wsb;                  //   reused after step 2 (16.8MB used)
    bf16* xraw  = wsb + NBI;              // pre-conv x  (b*s,i) 33.5MB
    bf16* gate  = wsb + 2 * NBI;          // gate        (b*s,i) 33.5MB
    bf16* xsb   = wsb + 3 * NBI;          // conv+silu x (b*s,i) 33.5MB
    bf16* yfin  = xraw;                   // reuse xraw after conv
    bf16*  dtin_bf = wsb + 4 * NBI;               // [h][bs][128] bf16, 2MB
    float* bc      = (float*)(dtin_bf + (long)NHH * BSF * RR); // [h][bs][32] 1MB
    bf16* up = wsb + (long)HH * II;               // upper half of inw slot
    float* Lbuf  = (float*)up;                            // 8.4MB
    float* sumdt = Lbuf + (long)CHUNKS * NCH * 16;        // 0.5MB
    bf16* xpw_pad = (bf16*)(sumdt + CHUNKS * NCH);        // [h][256][2048] 2MB
    bf16* dtw_bf  = xpw_pad + (long)NHH * 256 * HDD;      // [h][2048][128] 1MB
    // split-K partials: gate+xsb slots (dead after scan), contiguous 67MB
    float* kpart = (float*)gate;                          // [2][4096][2048] fp32
    bf16* hidden_bf = (bf16*)d_out;
    bf16* dtb       = (bf16*)d_out;

    static int attr_done = 0;
    if (!attr_done) {
        hipFuncSetAttribute(reinterpret_cast<const void*>(&gemm_8ph<0, 256>),
                            hipFuncAttributeMaxDynamicSharedMemorySize, 131072);
        hipFuncSetAttribute(reinterpret_cast<const void*>(&gemm_8ph<1, 256>),
                            hipFuncAttributeMaxDynamicSharedMemorySize, 131072);
        attr_done = 1;
    }

    // 1) casts needed for in_proj
    cast_f2b<<<(BSF * HH) / 1024, 256, 0, stream>>>(hidden, hidden_bf);
    cast_f2b<<<(2 * II * HH) / 1024, 256, 0, stream>>>(in_proj_w, inw_bf);

    // 2) in_proj 8-phase MFMA: de-interleave even/odd o -> xraw, gate
    gemm_8ph<0, 256><<<dim3(8192 / 256, BSF / 256, 1), 512, 131072, stream>>>(
        hidden_bf, inw_bf, xraw, gate, HH, HH, II);

    // 3) weight casts into the (now free) inw slot regions
    cast_f2b<<<(HH * II) / 1024, 256, 0, stream>>>(out_proj_w, outw_bf);
    cast_pad_xpw<<<(NHH * 256 * HDD) / 1024, 256, 0, stream>>>(x_proj_w, xpw_pad);
    cast_f2b<<<(NHH * HDD * RR) / 1024, 256, 0, stream>>>(dt_proj_w, dtw_bf);

    // 4) depthwise causal conv + SiLU
    conv_silu_kernel<<<(BSF * II) / 256, 256, 0, stream>>>(xraw, conv_w, conv_b, xsb);

    // 5) x_proj MFMA -> dtin (bf16) + bc (fp32 B/C)
    gemm_xp<<<dim3(2, BSF / 128, NHH), 256, 0, stream>>>(xsb, xpw_pad, dtin_bf, bc);

    // 6) dt MFMA + bias + softplus -> dtb (vectorized epilogue)
    gemm_dt<<<dim3(HDD / 128, BSF / 128, NHH), 256, 0, stream>>>(
        dtin_bf, dtw_bf, dt_proj_b, dtb);

    // 7) chunked selective scan + D skip + SiLU gating -> yfin (b*s, i)
    scan_part1<<<dim3(CHUNKS, HDD / 256, NHH * BB), 256, 0, stream>>>(
        dtb, xsb, bc, A_log, Lbuf, sumdt);
    scan_part2<<<(NCH * 16) / 256, 256, 0, stream>>>(A_log, Lbuf, sumdt);
    scan_part3<<<dim3(CHUNKS, HDD / 256, NHH * BB), 256, 0, stream>>>(
        dtb, xsb, gate, bc, A_log, Dp, Lbuf, yfin);

    // 8) out_proj: split-K=2 at BN=256 density (grid 8x16x2 = 256 blocks),
    //    fp32 partials -> kpart; then reduce into out.
    gemm_8ph<1, 256><<<dim3(HH / 256, BSF / 256, 2), 512, 131072, stream>>>(
        yfin, outw_bf, kpart, nullptr, II / 2, II, HH);
    addk<<<(BSF * HH) / 1024, 256, 0, stream>>>(kpart, out);
}

// Round 8
// 600.664 us; speedup vs baseline: 1.0381x; 1.0381x over previous
//
#include <hip/hip_runtime.h>
#include <hip/hip_bf16.h>

// ZambaMambaMixer: B=2,S=2048,H=2048 -> I=4096, N=16,K=4,R=128,NH=2,HD=2048.
// Dtype model T3 (confirmed R4): inputs fp32, output fp32. Intermediates bf16.
// R5: bf16-MFMA big GEMMs (m97 structure + XOR swizzle) + coalesced scan.
// R6: chunked parallel scan (16 chunks of 128), 810us -> ~60us.
// R7: x_proj/dt GEMMs -> MFMA; compact bc buffer for scan B/C.
// R8: in_proj -> 256x256 8-phase counted-vmcnt kernel (988 TF, 0 conflicts).
// R9: out_proj -> 8-phase BM256xBN128; scan 8-deep register prefetch.
// R10: FAILED one-barrier reg-prefetch schedule; exposed gemm_dt 162us.
// R11: R8 schedule restored; gemm_dt LDS-transpose epilogue (162 -> ~13us).
// R12: vmcnt at ph3/7 only (in_proj 138->133); split-K out_proj FAILED (+25:
//      fp32 partial+addk traffic ate the density gain).
// R13: (a) out_proj reverted to BN=128 8-phase, with ph3/7 vmcnt(3)
//      placement (drain table re-derived for the 2:1 A:B instr ratio).
//      (b) scan: geometric-dA fast path -- A_log=log(1..16) makes
//      exp(A_n*dt) = r^(n+1), r=exp(A_0*dt): 1 exp + 15 mul instead of
//      16 quarter-rate exps per step. Runtime-verified (uniform check,
//      generic fallback).
#define BB   2
#define SS   2048
#define HH   2048
#define II   4096
#define NHH  2
#define HDD  2048
#define NNS  16
#define RR   128
#define RN2  160
#define BSF  (BB*SS)   // 4096
#define CHUNKS 16
#define CT     (SS / CHUNKS)   // 128 timesteps per chunk
#define NCH    8192            // (h,b,d) channels = NHH*BB*HDD

typedef __hip_bfloat16 bf16;
typedef __attribute__((ext_vector_type(8))) short short8;
typedef __attribute__((ext_vector_type(4))) float floatx4;

__device__ inline float b2f(bf16 v) { return __bfloat162float(v); }
__device__ inline bf16  f2b(float v) { return __float2bfloat16(v); }

// async global->LDS, 16B per lane, lane L lands at ldsbase + L*16
__device__ inline void load_lds16(const bf16* g, short* l) {
    __builtin_amdgcn_global_load_lds(
        (const __attribute__((address_space(1))) void*)g,
        (__attribute__((address_space(3))) void*)l, 16, 0, 0);
}

// check Aval[n] == (n+1)*Aval[0] (the reference's A_log = log(1..N))
__device__ inline bool geo_check(const float* Aval) {
    bool g = true;
#pragma unroll
    for (int n = 1; n < 16; ++n) {
        const float ref = (n + 1) * Aval[0];
        g = g && (fabsf(Aval[n] - ref) <= 1e-5f * fabsf(ref) + 1e-7f);
    }
    return g;
}

// ---------------------------------------------------------------------------
// fp32 -> bf16 cast, 4 elems/thread
// ---------------------------------------------------------------------------
__global__ __launch_bounds__(256) void cast_f2b(
    const float* __restrict__ src, bf16* __restrict__ dst)
{
    const int idx = blockIdx.x * 256 + threadIdx.x;
    float4 v = ((const float4*)src)[idx];
    union { bf16 h[4]; uint2 u; } o;
    o.h[0] = f2b(v.x); o.h[1] = f2b(v.y); o.h[2] = f2b(v.z); o.h[3] = f2b(v.w);
    ((uint2*)dst)[idx] = o.u;
}

// x_proj_w cast with zero-padding: src [h][160][2048] -> dst [h][256][2048]
__global__ __launch_bounds__(256) void cast_pad_xpw(
    const float* __restrict__ src, bf16* __restrict__ dst)
{
    const int idx = blockIdx.x * 256 + threadIdx.x;   // over 2*256*2048/4
    const int e = idx * 4;
    const int h = e >> 19;            // 256*2048 = 2^19
    const int rem = e & ((1 << 19) - 1);
    const int row = rem >> 11;        // /2048
    union { bf16 hh[4]; uint2 u; } o;
    if (row < RN2) {
        float4 v = *(const float4*)(src + (long)h * RN2 * HDD + rem);
        o.hh[0] = f2b(v.x); o.hh[1] = f2b(v.y);
        o.hh[2] = f2b(v.z); o.hh[3] = f2b(v.w);
    } else {
        o.hh[0] = o.hh[1] = o.hh[2] = o.hh[3] = f2b(0.f);
    }
    ((uint2*)dst)[idx] = o.u;
}

// ---------------------------------------------------------------------------
// 8-phase BM=256 x BN=BROWS MFMA NT GEMM (T2+T3+T4+T5), R8 schedule with
// R12 vmcnt placement. 512 thr = 8 waves (2m x 4n), BK=64.
// LDS: As[2][2][256][32] + Bs[2][2][BROWS][32] bf16 (dynamic).
// Phase p: ds_read frags; stage one half-tile; p==3||p==7: vmcnt(4)
// [BROWS=256; (3) for 128]; barrier; lgkmcnt(0); setprio MFMA; barrier.
// Drain tables verified for both BROWS (incl. iter 0 via deep prologue
// drain): every region lands >=1 barrier before first read; WAR by barriers.
// MODE 0: n even -> C0, n odd -> C1 (bf16, col n/2, ldc). MODE 1: fp32.
// ---------------------------------------------------------------------------
template <int MODE, int BROWS>
__global__ __launch_bounds__(512) void gemm_8ph(
    const bf16* __restrict__ A, const bf16* __restrict__ B,
    void* __restrict__ C0v, void* __restrict__ C1v, int Kd, int ldc)
{
    constexpr int BNW = BROWS / 4;     // per-wave n cols
    constexpr int NFR = BNW / 16;      // b fragments per wave
    extern __shared__ short smem8[];
    short* As = smem8;                 // [2][2][256][32]
    short* Bs = smem8 + 32768;         // [2][2][BROWS][32]
    const int tid  = threadIdx.x;
    const int wave = tid >> 6, lane = tid & 63;
    const int wm = wave >> 2, wn = wave & 3;
    const int l15 = lane & 15, l4 = lane >> 4;
    const int coff = (l4 ^ ((l15 >> 1) & 3)) * 8;      // swizzled chunk (shorts)
    const int nt = blockIdx.x, mt = blockIdx.y;
    const long arow0 = (long)mt * 256, brow0 = (long)nt * BROWS;
    const int srow = lane >> 2;                        // staging row-in-16
    const int sgc  = (lane & 3) ^ ((lane >> 3) & 3);   // staging global chunk
    const int NT = Kd >> 6;
    const long ldk = Kd;

    floatx4 acc[8][NFR];
#pragma unroll
    for (int i = 0; i < 8; ++i)
#pragma unroll
        for (int j = 0; j < NFR; ++j) acc[i][j] = (floatx4){0.f, 0.f, 0.f, 0.f};

    auto stageA = [&](int slot, int kh, int t) {
        const int tc2 = (t < NT) ? t : (NT - 1);
        const long gb = ((long)tc2 << 6) + kh * 32 + sgc * 8;
#pragma unroll
        for (int j = 0; j < 2; ++j) {
            const int r0 = (wave * 2 + j) * 16;
            load_lds16(A + (arow0 + r0 + srow) * ldk + gb,
                       As + ((slot * 2 + kh) * 256 + r0) * 32);
        }
    };
    auto stageB = [&](int slot, int kh, int t) {
        const int tc2 = (t < NT) ? t : (NT - 1);
        const long gb = ((long)tc2 << 6) + kh * 32 + sgc * 8;
        if constexpr (BROWS == 256) {
#pragma unroll
            for (int j = 0; j < 2; ++j) {
                const int r0 = (wave * 2 + j) * 16;
                load_lds16(B + (brow0 + r0 + srow) * ldk + gb,
                           Bs + ((slot * 2 + kh) * 256 + r0) * 32);
            }
        } else {
            const int r0 = wave * 16;
            load_lds16(B + (brow0 + r0 + srow) * ldk + gb,
                       Bs + ((slot * 2 + kh) * 128 + r0) * 32);
        }
    };

    // prologue: tile0 (kh0,kh1) + tile1 (kh0); deep drain so regions (0,0)
    // AND (0,1) are landed before the loop (iter-0 safety for ph3/7 waits).
    stageA(0, 0, 0); stageB(0, 0, 0);
    stageA(0, 1, 0); stageB(0, 1, 0);
    stageA(1, 0, 1); stageB(1, 0, 1);
    if constexpr (BROWS == 256) asm volatile("s_waitcnt vmcnt(4)");
    else                        asm volatile("s_waitcnt vmcnt(3)");
    __builtin_amdgcn_s_barrier();

    short8 b_fr[NFR];
    const int NI = NT >> 1;
    for (int i = 0; i < NI; ++i) {
#pragma unroll
        for (int p = 0; p < 8; ++p) {
            const int cs = p >> 2, kh = (p >> 1) & 1, mh = p & 1;
            const int rbA = (cs * 2 + kh) * 256;
            const int rbB = (cs * 2 + kh) * BROWS;
            short8 a_fr[4];
#pragma unroll
            for (int q = 0; q < 4; ++q)
                a_fr[q] = *(const short8*)(
                    As + (rbA + wm * 128 + (mh * 4 + q) * 16 + l15) * 32 + coff);
            if (mh == 0) {
#pragma unroll
                for (int g = 0; g < NFR; ++g)
                    b_fr[g] = *(const short8*)(
                        Bs + (rbB + wn * BNW + g * 16 + l15) * 32 + coff);
            }
            // staging table (region free'd >=1 barrier before; read later)
            if      (p == 0) stageA(1, 1, 2 * i + 1);
            else if (p == 1) stageB(1, 1, 2 * i + 1);
            else if (p == 2) stageA(0, 0, 2 * i + 2);
            else if (p == 3) stageB(0, 0, 2 * i + 2);
            else if (p == 4) stageA(0, 1, 2 * i + 2);
            else if (p == 5) stageB(0, 1, 2 * i + 2);
            else if (p == 6) stageA(1, 0, 2 * i + 3);
            else             stageB(1, 0, 2 * i + 3);
            if (p == 3 || p == 7) {
                if constexpr (BROWS == 256)
                    asm volatile("s_waitcnt vmcnt(4)");
                else
                    asm volatile("s_waitcnt vmcnt(3)");
            }
            __builtin_amdgcn_s_barrier();
            asm volatile("s_waitcnt lgkmcnt(0)");
            __builtin_amdgcn_sched_barrier(0);
            __builtin_amdgcn_s_setprio(1);
#pragma unroll
            for (int q = 0; q < 4; ++q)
#pragma unroll
                for (int g = 0; g < NFR; ++g)
                    acc[mh * 4 + q][g] = __builtin_amdgcn_mfma_f32_16x16x32_bf16(
                        a_fr[q], b_fr[g], acc[mh * 4 + q][g], 0, 0, 0);
            __builtin_amdgcn_s_setprio(0);
            __builtin_amdgcn_s_barrier();
        }
    }

#pragma unroll
    for (int f = 0; f < 8; ++f)
#pragma unroll
        for (int g = 0; g < NFR; ++g) {
            const int gcol = nt * BROWS + wn * BNW + g * 16 + l15;
#pragma unroll
            for (int r = 0; r < 4; ++r) {
                const int grow = mt * 256 + wm * 128 + f * 16 + l4 * 4 + r;
                const float v = acc[f][g][r];
                if (MODE == 0) {
                    bf16* buf = (gcol & 1) ? (bf16*)C1v : (bf16*)C0v;
                    buf[(long)grow * ldc + (gcol >> 1)] = f2b(v);
                } else {
                    ((float*)C0v)[(long)grow * ldc + gcol] = v;
                }
            }
        }
}

// ---------------------------------------------------------------------------
// x_proj MFMA: per head h, C[bs][r] = sum_k xsb[bs][h*HD+k] * xpw[h][r][k].
// r<128 -> dtin bf16 [h][bs][128]; 128<=r<160 -> bc fp32 [h][bs][32]; else skip.
// ---------------------------------------------------------------------------
__global__ __launch_bounds__(256) void gemm_xp(
    const bf16* __restrict__ Abase, const bf16* __restrict__ Bbase,
    bf16* __restrict__ dtin, float* __restrict__ bc)
{
    const int h = blockIdx.z;
    const bf16* A = Abase + (long)h * HDD;           // lda = II
    const bf16* B = Bbase + (long)h * 256 * HDD;     // ldb = HDD
    bf16*  C0 = dtin + (long)h * BSF * RR;
    float* C1 = bc   + (long)h * BSF * 32;
    __shared__ short Asm[128 * 32];
    __shared__ short Bsm[128 * 32];
    const int tid  = threadIdx.x;
    const int wave = tid >> 6, lane = tid & 63;
    const int wr = wave >> 1, wc = wave & 1;
    const int mt = blockIdx.y, nt = blockIdx.x;
    const int rl = lane >> 2, slot = lane & 3;
    const int gchunk = slot ^ ((rl >> 1) & 3);
    const int l15 = lane & 15, l4 = lane >> 4;
    const int coff = (l4 ^ ((l15 >> 1) & 3)) * 8;

    floatx4 acc[4][4];
#pragma unroll
    for (int i = 0; i < 4; ++i)
#pragma unroll
        for (int j = 0; j < 4; ++j) acc[i][j] = (floatx4){0.f, 0.f, 0.f, 0.f};

    for (int kt = 0; kt < HDD; kt += 32) {
#pragma unroll
        for (int half = 0; half < 2; ++half) {
            const int row = wave * 32 + half * 16 + rl;
            load_lds16(A + (long)(mt * 128 + row) * II + kt + gchunk * 8,
                       Asm + (wave * 32 + half * 16) * 32);
            load_lds16(B + (long)(nt * 128 + row) * HDD + kt + gchunk * 8,
                       Bsm + (wave * 32 + half * 16) * 32);
        }
        __syncthreads();
        short8 af[4], bf[4];
#pragma unroll
        for (int f = 0; f < 4; ++f) {
            const int ra = wr * 64 + f * 16 + l15;
            const int rb = wc * 64 + f * 16 + l15;
            af[f] = *(const short8*)(Asm + ra * 32 + coff);
            bf[f] = *(const short8*)(Bsm + rb * 32 + coff);
        }
#pragma unroll
        for (int fm = 0; fm < 4; ++fm)
#pragma unroll
            for (int fn = 0; fn < 4; ++fn)
                acc[fm][fn] = __builtin_amdgcn_mfma_f32_16x16x32_bf16(
                    af[fm], bf[fn], acc[fm][fn], 0, 0, 0);
        __syncthreads();
    }

#pragma unroll
    for (int fm = 0; fm < 4; ++fm)
#pragma unroll
        for (int fn = 0; fn < 4; ++fn) {
            const int gcol = nt * 128 + wc * 64 + fn * 16 + l15;   // r-dim
#pragma unroll
            for (int r = 0; r < 4; ++r) {
                const int grow = mt * 128 + wr * 64 + fm * 16 + l4 * 4 + r; // bs
                const float v = acc[fm][fn][r];
                if (gcol < RR)
                    C0[(long)grow * RR + gcol] = f2b(v);
                else if (gcol < RN2)
                    C1[(long)grow * 32 + (gcol - RR)] = v;
            }
        }
}

// ---------------------------------------------------------------------------
// dt MFMA: per head h, C[bs][d] = sum_r dtin[h][bs][r] * dtw[h][d][r];
// then softplus(C + bias[h][d]) -> dtb[bs][h*HD+d] bf16.
// R11 epilogue: LDS transpose (float[128][33]) + __logf(1+__expf(v)) +
// 16-contiguous-bf16 stores.
// ---------------------------------------------------------------------------
__global__ __launch_bounds__(256) void gemm_dt(
    const bf16* __restrict__ dtin, const bf16* __restrict__ dtw,
    const float* __restrict__ bias, bf16* __restrict__ dtb)
{
    const int h = blockIdx.z;
    const bf16* A = dtin + (long)h * BSF * RR;   // lda = RR
    const bf16* B = dtw  + (long)h * HDD * RR;   // ldb = RR
    __shared__ float smemf[128 * 33];            // 16.9KB; aliased by staging
    short* Asm = (short*)smemf;                  // 128*32 shorts = 8KB
    short* Bsm = Asm + 128 * 32;                 // 8KB
    const int tid  = threadIdx.x;
    const int wave = tid >> 6, lane = tid & 63;
    const int wr = wave >> 1, wc = wave & 1;
    const int mt = blockIdx.y, nt = blockIdx.x;
    const int rl = lane >> 2, slot = lane & 3;
    const int gchunk = slot ^ ((rl >> 1) & 3);
    const int l15 = lane & 15, l4 = lane >> 4;
    const int coff = (l4 ^ ((l15 >> 1) & 3)) * 8;

    floatx4 acc[4][4];
#pragma unroll
    for (int i = 0; i < 4; ++i)
#pragma unroll
        for (int j = 0; j < 4; ++j) acc[i][j] = (floatx4){0.f, 0.f, 0.f, 0.f};

    for (int kt = 0; kt < RR; kt += 32) {
#pragma unroll
        for (int half = 0; half < 2; ++half) {
            const int row = wave * 32 + half * 16 + rl;
            load_lds16(A + (long)(mt * 128 + row) * RR + kt + gchunk * 8,
                       Asm + (wave * 32 + half * 16) * 32);
            load_lds16(B + (long)(nt * 128 + row) * RR + kt + gchunk * 8,
                       Bsm + (wave * 32 + half * 16) * 32);
        }
        __syncthreads();
        short8 af[4], bf[4];
#pragma unroll
        for (int f = 0; f < 4; ++f) {
            const int ra = wr * 64 + f * 16 + l15;
            const int rb = wc * 64 + f * 16 + l15;
            af[f] = *(const short8*)(Asm + ra * 32 + coff);
            bf[f] = *(const short8*)(Bsm + rb * 32 + coff);
        }
#pragma unroll
        for (int fm = 0; fm < 4; ++fm)
#pragma unroll
            for (int fn = 0; fn < 4; ++fn)
                acc[fm][fn] = __builtin_amdgcn_mfma_f32_16x16x32_bf16(
                    af[fm], bf[fn], acc[fm][fn], 0, 0, 0);
        __syncthreads();
    }

    // epilogue: 4 passes (one per fn); LDS col c' = wc*16+l15 maps to
    // global col nt*128 + (c'>>4)*64 + p*16 + (c'&15).
    const int row = tid >> 1, chf = tid & 1;
#pragma unroll
    for (int p = 0; p < 4; ++p) {
        __syncthreads();
#pragma unroll
        for (int fm = 0; fm < 4; ++fm)
#pragma unroll
            for (int r = 0; r < 4; ++r)
                smemf[(wr * 64 + fm * 16 + l4 * 4 + r) * 33 + wc * 16 + l15] =
                    acc[fm][p][r];
        __syncthreads();
        float vv[16];
#pragma unroll
        for (int q = 0; q < 4; ++q)
            *(float4*)&vv[q * 4] =
                *(const float4*)&smemf[row * 33 + chf * 16 + q * 4];
        const int gc0 = nt * 128 + chf * 64 + p * 16;
        const float* bp = bias + h * HDD + gc0;
        union { bf16 hh[16]; uint4 u4[2]; } o;
#pragma unroll
        for (int j = 0; j < 16; ++j) {
            float v = vv[j] + bp[j];
            v = (v > 20.f) ? v : __logf(1.f + __expf(v));
            o.hh[j] = f2b(v);
        }
        bf16* dst = dtb + (long)(mt * 128 + row) * II + h * HDD + gc0;
        *(uint4*)dst = o.u4[0];
        *(uint4*)(dst + 8) = o.u4[1];
    }
}

// ---------------------------------------------------------------------------
// Depthwise causal conv (K=4) + bias + SiLU. Layout (b*s, i), i contiguous.
// ---------------------------------------------------------------------------
__global__ __launch_bounds__(256) void conv_silu_kernel(
    const bf16* __restrict__ xraw, const float* __restrict__ conv_w,
    const float* __restrict__ conv_b, bf16* __restrict__ xs)
{
    const int idx = blockIdx.x * 256 + threadIdx.x;  // over BSF*II
    const int i  = idx & (II - 1);
    const int bs = idx >> 12;
    const int s  = bs & (SS - 1);
    const float4 cw = ((const float4*)conv_w)[i];
    float v = conv_b[i];
    const bf16* col = xraw + (long)bs * II + i;
    if (s >= 3) v = fmaf(b2f(col[-3 * II]), cw.x, v);
    if (s >= 2) v = fmaf(b2f(col[-2 * II]), cw.y, v);
    if (s >= 1) v = fmaf(b2f(col[-1 * II]), cw.z, v);
    v = fmaf(b2f(col[0]), cw.w, v);
    xs[idx] = f2b(v / (1.f + __expf(-v)));
}

// ---------------------------------------------------------------------------
// Chunked selective scan (R6). B/C from compact bc buffer [h][bs][32] fp32.
// R9: 8-deep register prefetch of dt/x(/gate).
// R13: geometric-dA fast path (1 exp + 15 mul instead of 16 exps).
// ---------------------------------------------------------------------------
__global__ __launch_bounds__(256) void scan_part1(
    const bf16* __restrict__ dtb, const bf16* __restrict__ xs,
    const float* __restrict__ bc, const float* __restrict__ A_log,
    float* __restrict__ Lbuf, float* __restrict__ sumdt)
{
    __shared__ float Bs[64][16];
    const int tid = threadIdx.x;
    const int c = blockIdx.x, dblk = blockIdx.y, hb = blockIdx.z;
    const int h = hb >> 1, b = hb & 1;
    const int d = dblk * 256 + tid;
    const int i = h * HDD + d;
    const int ch = hb * HDD + d;

    float st[16], Aval[16];
#pragma unroll
    for (int n = 0; n < 16; ++n) {
        Aval[n] = -__expf(A_log[(long)i * NNS + n]);
        st[n] = 0.f;
    }
    const bool geo = geo_check(Aval);
    const long rowbase = (long)h * BSF + (long)b * SS + c * CT;
    const long pbase = ((long)b * SS + (long)c * CT) * II + i;
    float sdt = 0.f;
    bf16 cd[8], cx[8];
#pragma unroll
    for (int j = 0; j < 8; ++j) {
        cd[j] = dtb[pbase + (long)j * II];
        cx[j] = xs [pbase + (long)j * II];
    }

    const int sr = tid >> 2, sq = tid & 3;
    for (int tc = 0; tc < CT; tc += 64) {
        __syncthreads();
        {
            const float* src = bc + (rowbase + tc + sr) * 32 + sq * 4;
            *(float4*)&Bs[sr][sq * 4] = *(const float4*)src;
        }
        __syncthreads();
        for (int tg = 0; tg < 64; tg += 8) {
            bf16 nd[8], nx[8];
            const int tn0 = tc + tg + 8;
#pragma unroll
            for (int j = 0; j < 8; ++j) {
                int tt = tn0 + j; tt = (tt < CT) ? tt : (CT - 1);
                nd[j] = dtb[pbase + (long)tt * II];
                nx[j] = xs [pbase + (long)tt * II];
            }
#pragma unroll
            for (int j = 0; j < 8; ++j) {
                const int tl = tg + j;
                const float dtv = b2f(cd[j]);
                const float dtx = dtv * b2f(cx[j]);
                float fB[16];
#pragma unroll
                for (int q = 0; q < 4; ++q)
                    *(float4*)&fB[q * 4] = *(const float4*)&Bs[tl][q * 4];
                float dA[16];
                if (geo) {
                    const float r = __expf(Aval[0] * dtv);
                    float pw = r;
#pragma unroll
                    for (int n = 0; n < 16; ++n) { dA[n] = pw; pw *= r; }
                } else {
#pragma unroll
                    for (int n = 0; n < 16; ++n) dA[n] = __expf(Aval[n] * dtv);
                }
#pragma unroll
                for (int n = 0; n < 16; ++n)
                    st[n] = fmaf(dA[n], st[n], dtx * fB[n]);
                sdt += dtv;
            }
#pragma unroll
            for (int j = 0; j < 8; ++j) { cd[j] = nd[j]; cx[j] = nx[j]; }
        }
    }
    float* Lp = Lbuf + ((long)c * NCH + ch) * 16;
#pragma unroll
    for (int j = 0; j < 4; ++j)
        *(float4*)&Lp[j * 4] = *(const float4*)&st[j * 4];
    sumdt[c * NCH + ch] = sdt;
}

__global__ __launch_bounds__(256) void scan_part2(
    const float* __restrict__ A_log, float* __restrict__ Lbuf,
    const float* __restrict__ sumdt)
{
    const int gid = blockIdx.x * 256 + threadIdx.x;  // NCH*16 threads
    const int ch = gid >> 4, n = gid & 15;
    const int hb = ch >> 11, d = ch & (HDD - 1);
    const int h = hb >> 1;
    const float Aval = -__expf(A_log[(long)(h * HDD + d) * NNS + n]);
    float run = 0.f;
#pragma unroll
    for (int c = 0; c < CHUNKS; ++c) {
        const long idx = ((long)c * NCH + ch) * 16 + n;
        const float Lv  = Lbuf[idx];
        const float sdt = sumdt[c * NCH + ch];
        Lbuf[idx] = run;                         // entry state for chunk c
        run = fmaf(__expf(Aval * sdt), run, Lv); // compose chunk c
    }
}

__global__ __launch_bounds__(256) void scan_part3(
    const bf16* __restrict__ dtb, const bf16* __restrict__ xs,
    const bf16* __restrict__ gate, const float* __restrict__ bc,
    const float* __restrict__ A_log, const float* __restrict__ Dp,
    const float* __restrict__ Lbuf, bf16* __restrict__ yfin)
{
    __shared__ float Bs[64][16];
    __shared__ float Cs[64][16];
    const int tid = threadIdx.x;
    const int c = blockIdx.x, dblk = blockIdx.y, hb = blockIdx.z;
    const int h = hb >> 1, b = hb & 1;
    const int d = dblk * 256 + tid;
    const int i = h * HDD + d;
    const int ch = hb * HDD + d;

    float st[16], Aval[16];
    const float* Lp = Lbuf + ((long)c * NCH + ch) * 16;
#pragma unroll
    for (int j = 0; j < 4; ++j)
        *(float4*)&st[j * 4] = *(const float4*)&Lp[j * 4];
#pragma unroll
    for (int n = 0; n < 16; ++n)
        Aval[n] = -__expf(A_log[(long)i * NNS + n]);
    const bool geo = geo_check(Aval);
    const float Dv = Dp[i];

    const long rowbase = (long)h * BSF + (long)b * SS + c * CT;
    const long pbase = ((long)b * SS + (long)c * CT) * II + i;
    bf16 cd[8], cx[8], cg[8];
#pragma unroll
    for (int j = 0; j < 8; ++j) {
        cd[j] = dtb [pbase + (long)j * II];
        cx[j] = xs  [pbase + (long)j * II];
        cg[j] = gate[pbase + (long)j * II];
    }

    const int sr = tid >> 2, sq = tid & 3;
    for (int tc = 0; tc < CT; tc += 64) {
        __syncthreads();
        {
            const float* src = bc + (rowbase + tc + sr) * 32 + sq * 4;
            float4 bb = *(const float4*)src;
            float4 cc = *(const float4*)(src + 16);
            *(float4*)&Bs[sr][sq * 4] = bb;
            *(float4*)&Cs[sr][sq * 4] = cc;
        }
        __syncthreads();
        for (int tg = 0; tg < 64; tg += 8) {
            bf16 nd[8], nx[8], ng[8];
            const int tn0 = tc + tg + 8;
#pragma unroll
            for (int j = 0; j < 8; ++j) {
                int tt = tn0 + j; tt = (tt < CT) ? tt : (CT - 1);
                nd[j] = dtb [pbase + (long)tt * II];
                nx[j] = xs  [pbase + (long)tt * II];
                ng[j] = gate[pbase + (long)tt * II];
            }
            const long prow = pbase + (long)(tc + tg) * II;
#pragma unroll
            for (int j = 0; j < 8; ++j) {
                const int tl = tg + j;
                const float dtv = b2f(cd[j]);
                const float xv  = b2f(cx[j]);
                const float gv  = b2f(cg[j]);
                const float dtx = dtv * xv;
                float fB[16], fC[16];
#pragma unroll
                for (int q = 0; q < 4; ++q) {
                    *(float4*)&fB[q * 4] = *(const float4*)&Bs[tl][q * 4];
                    *(float4*)&fC[q * 4] = *(const float4*)&Cs[tl][q * 4];
                }
                float dA[16];
                if (geo) {
                    const float r = __expf(Aval[0] * dtv);
                    float pw = r;
#pragma unroll
                    for (int n = 0; n < 16; ++n) { dA[n] = pw; pw *= r; }
                } else {
#pragma unroll
                    for (int n = 0; n < 16; ++n) dA[n] = __expf(Aval[n] * dtv);
                }
                float y = 0.f;
#pragma unroll
                for (int n = 0; n < 16; ++n) {
                    st[n] = fmaf(dA[n], st[n], dtx * fB[n]);
                    y = fmaf(st[n], fC[n], y);
                }
                const float sg = gv / (1.f + __expf(-gv));
                yfin[prow + (long)j * II] = f2b((y + xv * Dv) * sg);
            }
#pragma unroll
            for (int j = 0; j < 8; ++j) { cd[j] = nd[j]; cx[j] = nx[j]; cg[j] = ng[j]; }
        }
    }
}

// ---------------------------------------------------------------------------
extern "C" void kernel_launch(void* const* d_in, const int* in_sizes, int n_in,
                              void* d_out, int out_size, void* d_ws, size_t ws_size,
                              hipStream_t stream) {
    const float* hidden     = (const float*)d_in[0];
    const float* in_proj_w  = (const float*)d_in[1];
    const float* conv_w     = (const float*)d_in[2];
    const float* conv_b     = (const float*)d_in[3];
    const float* x_proj_w   = (const float*)d_in[4];
    const float* dt_proj_w  = (const float*)d_in[5];
    const float* dt_proj_b  = (const float*)d_in[6];
    const float* A_log      = (const float*)d_in[7];
    const float* Dp         = (const float*)d_in[8];
    const float* out_proj_w = (const float*)d_in[9];
    float* out = (float*)d_out;

    const long NBI = (long)BSF * II;      // 16,777,216
    bf16* wsb   = (bf16*)d_ws;
    bf16* inw_bf  = wsb;                  // [0, 16.8M) : in_proj_w bf16, 33.5MB
    bf16* outw_bf = wsb;                  //   reused after step 2 (16.8MB used)
    bf16* xraw  = wsb + NBI;              // pre-conv x  (b*s,i) 33.5MB
    bf16* gate  = wsb + 2 * NBI;          // gate        (b*s,i) 33.5MB
    bf16* xsb   = wsb + 3 * NBI;          // conv+silu x (b*s,i) 33.5MB
    bf16* yfin  = xraw;                   // reuse xraw after conv
    bf16*  dtin_bf = wsb + 4 * NBI;               // [h][bs][128] bf16, 2MB
    float* bc      = (float*)(dtin_bf + (long)NHH * BSF * RR); // [h][bs][32] 1MB
    bf16* up = wsb + (long)HH * II;               // upper half of inw slot
    float* Lbuf  = (float*)up;                            // 8.4MB
    float* sumdt = Lbuf + (long)CHUNKS * NCH * 16;        // 0.5MB
    bf16* xpw_pad = (bf16*)(sumdt + CHUNKS * NCH);        // [h][256][2048] 2MB
    bf16* dtw_bf  = xpw_pad + (long)NHH * 256 * HDD;      // [h][2048][128] 1MB
    bf16* hidden_bf = (bf16*)d_out;
    bf16* dtb       = (bf16*)d_out;

    static int attr_done = 0;
    if (!attr_done) {
        hipFuncSetAttribute(reinterpret_cast<const void*>(&gemm_8ph<0, 256>),
                            hipFuncAttributeMaxDynamicSharedMemorySize, 131072);
        hipFuncSetAttribute(reinterpret_cast<const void*>(&gemm_8ph<1, 128>),
                            hipFuncAttributeMaxDynamicSharedMemorySize, 98304);
        attr_done = 1;
    }

    // 1) casts needed for in_proj
    cast_f2b<<<(BSF * HH) / 1024, 256, 0, stream>>>(hidden, hidden_bf);
    cast_f2b<<<(2 * II * HH) / 1024, 256, 0, stream>>>(in_proj_w, inw_bf);

    // 2) in_proj 8-phase MFMA: de-interleave even/odd o -> xraw, gate
    gemm_8ph<0, 256><<<dim3(8192 / 256, BSF / 256), 512, 131072, stream>>>(
        hidden_bf, inw_bf, xraw, gate, HH, II);

    // 3) weight casts into the (now free) inw slot regions
    cast_f2b<<<(HH * II) / 1024, 256, 0, stream>>>(out_proj_w, outw_bf);
    cast_pad_xpw<<<(NHH * 256 * HDD) / 1024, 256, 0, stream>>>(x_proj_w, xpw_pad);
    cast_f2b<<<(NHH * HDD * RR) / 1024, 256, 0, stream>>>(dt_proj_w, dtw_bf);

    // 4) depthwise causal conv + SiLU
    conv_silu_kernel<<<(BSF * II) / 256, 256, 0, stream>>>(xraw, conv_w, conv_b, xsb);

    // 5) x_proj MFMA -> dtin (bf16) + bc (fp32 B/C)
    gemm_xp<<<dim3(2, BSF / 128, NHH), 256, 0, stream>>>(xsb, xpw_pad, dtin_bf, bc);

    // 6) dt MFMA + bias + softplus -> dtb (vectorized epilogue)
    gemm_dt<<<dim3(HDD / 128, BSF / 128, NHH), 256, 0, stream>>>(
        dtin_bf, dtw_bf, dt_proj_b, dtb);

    // 7) chunked selective scan + D skip + SiLU gating -> yfin (b*s, i)
    scan_part1<<<dim3(CHUNKS, HDD / 256, NHH * BB), 256, 0, stream>>>(
        dtb, xsb, bc, A_log, Lbuf, sumdt);
    scan_part2<<<(NCH * 16) / 256, 256, 0, stream>>>(A_log, Lbuf, sumdt);
    scan_part3<<<dim3(CHUNKS, HDD / 256, NHH * BB), 256, 0, stream>>>(
        dtb, xsb, gate, bc, A_log, Dp, Lbuf, yfin);

    // 8) out_proj 8-phase MFMA (BM=256 x BN=128, 256 blocks): fp32 store
    gemm_8ph<1, 128><<<dim3(HH / 128, BSF / 256), 512, 98304, stream>>>(
        yfin, outw_bf, out, nullptr, II, HH);
}